// Round 6
// baseline (2993967.773 us; speedup 1.0000x reference)
//
#include <hip/hip_runtime.h>
#include <cfloat>
#include <cmath>

#define E      512
#define FOURE  2048
#define VT     50000
#define SLEN   128
#define TLEN   129            // decoder steps (targets + EOS)
#define NSTEPS 257
#define NB     64             // workers (one XCD: 32 CUs x 2 blocks)
#define NGRID  512            // launched blocks; >=64 land on the chosen XCD
#define NCHUNK 196
#define TPAD   132

#define SENT_U32 0x40404040u  // 3.0039f: impossible h value (|h| < 1)

// ---- workspace layout (bytes); total 2,369,664 <= 2,597,572 proven (r1) ----
#define HS_OFF     0            // hsteps[s], 2048 B each, s=0..257
#define POISON_B   264192       // host poisons s in [0,129) with 0x40
#define GXE_OFF    264192       // 128*2048 f32; HEAD aliased by hsteps[129..257]
#define GXD_OFF    1312768      // 129*2048 f32 -> ends 2369536
#define HALL_OFF   264192       // = hsteps[129] = decoder h history [129][512]
#define PM_OFF     0            // c1 partials alias dead hsteps region
#define PS_OFF     103488
#define TL_OFF     206976       // ends 207492
#define REG_OFF    2369536      // chosen/cnt/mode (zeroed); OUTSIDE poison region
#define WS_TOTAL   2369664

__device__ __forceinline__ float sigf(float x){ return 1.0f/(1.0f+__expf(-x)); }
__device__ __forceinline__ float tanhf_fast(float x){ return 2.f*sigf(2.f*x) - 1.f; }

#define KEEPW(w) do{ \
  asm volatile("" : "+v"(w[0]),"+v"(w[1]),"+v"(w[2]),"+v"(w[3]),"+v"(w[4]),"+v"(w[5]),"+v"(w[6]),"+v"(w[7]), \
                    "+v"(w[8]),"+v"(w[9]),"+v"(w[10]),"+v"(w[11]),"+v"(w[12]),"+v"(w[13]),"+v"(w[14]),"+v"(w[15])); \
  asm volatile("" : "+v"(w[16]),"+v"(w[17]),"+v"(w[18]),"+v"(w[19]),"+v"(w[20]),"+v"(w[21]),"+v"(w[22]),"+v"(w[23]), \
                    "+v"(w[24]),"+v"(w[25]),"+v"(w[26]),"+v"(w[27]),"+v"(w[28]),"+v"(w[29]),"+v"(w[30]),"+v"(w[31])); \
}while(0)

// =================== A: Gx[t][r] = x_t @ W_ih^T + b_ih + b_hh ===================
__global__ __launch_bounds__(256) void gx_kernel(
    const int* __restrict__ src, const int* __restrict__ tgt,
    const float* __restrict__ Wx, const float* __restrict__ Wy,
    const float* __restrict__ encWih, const float* __restrict__ encBih, const float* __restrict__ encBhh,
    const float* __restrict__ decWih, const float* __restrict__ decBih, const float* __restrict__ decBhh,
    float* __restrict__ GxE, float* __restrict__ GxD)
{
  __shared__ float xs[8][E];
  const int tid  = threadIdx.x;
  const int tile = blockIdx.x;
  const bool is_dec = tile >= 16;
  const int t0 = is_dec ? (tile-16)*8 : tile*8;
  const int T  = is_dec ? TLEN : SLEN;

  for (int tt=0; tt<8; ++tt){
    int t = t0+tt;
    if (t < T){
      const float* xrow;
      if (is_dec) xrow = (t==0) ? (Wx + (size_t)1*E) : (Wy + (size_t)tgt[t-1]*E);
      else        xrow = Wx + (size_t)src[t]*E;
      xs[tt][tid]     = xrow[tid];
      xs[tt][tid+256] = xrow[tid+256];
    }
  }
  __syncthreads();

  const int r = blockIdx.y*256 + tid;
  const float* wrow = (is_dec ? decWih : encWih) + (size_t)r*E;
  const float  bias = is_dec ? (decBih[r]+decBhh[r]) : (encBih[r]+encBhh[r]);
  float acc[8];
  #pragma unroll
  for (int i=0;i<8;++i) acc[i]=0.f;

  for (int kc=0; kc<E; kc+=4){
    float4 w = *(const float4*)(wrow+kc);
    #pragma unroll
    for (int tt=0; tt<8; ++tt){
      float4 x = *(const float4*)&xs[tt][kc];
      acc[tt] += w.x*x.x + w.y*x.y + w.z*x.z + w.w*x.w;
    }
  }
  float* Gx = is_dec ? GxD : GxE;
  #pragma unroll
  for (int tt=0; tt<8; ++tt){
    int t = t0+tt;
    if (t < T) Gx[(size_t)t*FOURE + r] = bias + acc[tt];
  }
}

// =================== B: single-XCD LSTM (L2-local dataflow) ===================
__device__ __forceinline__ void loadw(const float* __restrict__ Whh, int row, int k, float (&w)[32]){
  const float4* p = (const float4*)(Whh + (size_t)row*E + 32*k);
  #pragma unroll
  for (int i=0;i<8;++i){
    float4 t = p[i];
    w[4*i]=t.x; w[4*i+1]=t.y; w[4*i+2]=t.z; w[4*i+3]=t.w;
  }
}

// LDS h mirror: padded index pidx(c) = c + 4*(c>>5); stride 36 floats per k-slice
// (144 B: 16B-aligned, banks (4k+4i)%32 -> worst 2-way = free).
__device__ __forceinline__ void fast_step(
    int s, int tloc, const float* __restrict__ Gx,
    float* __restrict__ hsteps, float (*hl)[576], unsigned* ltag,
    float (&w)[32], int lane, int wave, int g, int k, int j, int row, float& cst)
{
  KEEPW(w);                                     // scalars stay VGPR-resident
  float gx = Gx[(size_t)tloc*FOURE + row];      // issued early, used late
  float acc = 0.f;

  if (s > 0){
    const int buf = s & 1;
    if (wave == 0){
      // wave0 polls the full 2 KB h[s] from global (sc0 = L2-coherent in-XCD)
      const unsigned* p = (const unsigned*)hsteps + (size_t)s*E + 8*lane;
      uint4 a, b;
      for (int spin=0; spin<(1<<16); ++spin){
        asm volatile(
          "global_load_dwordx4 %0, %2, off sc0\n\t"
          "global_load_dwordx4 %1, %2, off offset:16 sc0\n\t"
          "s_waitcnt vmcnt(0)"
          : "=&v"(a), "=&v"(b) : "v"(p) : "memory");
        bool ok = (a.x!=SENT_U32)&&(a.y!=SENT_U32)&&(a.z!=SENT_U32)&&(a.w!=SENT_U32)
               && (b.x!=SENT_U32)&&(b.y!=SENT_U32)&&(b.z!=SENT_U32)&&(b.w!=SENT_U32);
        if (__all(ok)) break;
        __builtin_amdgcn_s_sleep(1);
      }
      float* d = &hl[buf][8*lane + 4*(lane>>2)];
      *(float4*)d       = *(float4*)&a;
      *(float4*)(d + 4) = *(float4*)&b;
      __hip_atomic_store(&ltag[buf], (unsigned)s, __ATOMIC_RELEASE, __HIP_MEMORY_SCOPE_WORKGROUP);
    }
    for (int spin=0; spin<(1<<20); ++spin){
      if (__hip_atomic_load(&ltag[buf], __ATOMIC_ACQUIRE, __HIP_MEMORY_SCOPE_WORKGROUP) == (unsigned)s) break;
    }
    const float* hb = &hl[buf][36*k];
    #pragma unroll
    for (int i=0;i<8;++i){
      float4 h4 = *(const float4*)(hb + 4*i);
      acc += w[4*i]*h4.x + w[4*i+1]*h4.y + w[4*i+2]*h4.z + w[4*i+3]*h4.w;
    }
    acc += __shfl_xor(acc,1); acc += __shfl_xor(acc,2);
    acc += __shfl_xor(acc,4); acc += __shfl_xor(acc,8);
  }

  float gv = acc + gx;
  float x1 = __shfl_xor(gv,16);
  float x2 = __shfl_xor(gv,32);
  float x3 = __shfl_xor(x1,32);
  float gi = (g==0)?gv:(g==1)?x1:(g==2)?x2:x3;
  float gf = (g==0)?x1:(g==1)?gv:(g==2)?x3:x2;
  float gg = (g==0)?x2:(g==1)?x3:(g==2)?gv:x1;
  float go = (g==0)?x3:(g==1)?x2:(g==2)?x1:gv;
  cst = sigf(gf)*cst + sigf(gi)*tanhf_fast(gg);
  float hnew = sigf(go)*tanhf_fast(cst);

  if (lane==0){
    float* dst = hsteps + (size_t)(s+1)*E + j;
    asm volatile("global_store_dword %0, %1, off sc0" :: "v"(dst), "v"(hnew) : "memory");
  }
}

// correctness fallback: one block computes everything (slow but bounded)
__device__ void fallback_lstm(
    const float* __restrict__ GxE, const float* __restrict__ GxD,
    const float* __restrict__ encWhh, const float* __restrict__ decWhh,
    float* __restrict__ hsteps, float* hcur)
{
  const int tid = threadIdx.x;                 // 512 threads; j = tid
  hcur[tid] = 0.f; __syncthreads();
  float cst = 0.f;
  for (int s=0; s<NSTEPS; ++s){
    const bool isdec = s >= SLEN;
    if (s == SLEN) cst = 0.f;
    const int tloc = isdec ? s-SLEN : s;
    const float* Whh = isdec ? decWhh : encWhh;
    const float* Gx  = isdec ? GxD : GxE;
    float gv4[4];
    #pragma unroll
    for (int g4=0; g4<4; ++g4){
      const float* wr = Whh + (size_t)(g4*E + tid)*E;
      float acc = 0.f;
      for (int kk=0; kk<E; kk+=4){
        float4 wv = *(const float4*)(wr+kk);
        acc += wv.x*hcur[kk] + wv.y*hcur[kk+1] + wv.z*hcur[kk+2] + wv.w*hcur[kk+3];
      }
      gv4[g4] = acc + Gx[(size_t)tloc*FOURE + g4*E + tid];
    }
    cst = sigf(gv4[1])*cst + sigf(gv4[0])*tanhf_fast(gv4[2]);
    float hnew = sigf(gv4[3])*tanhf_fast(cst);
    __syncthreads();
    hcur[tid] = hnew;
    float* dst = hsteps + (size_t)(s+1)*E + tid;
    asm volatile("global_store_dword %0, %1, off sc0" :: "v"(dst), "v"(hnew) : "memory");
    __syncthreads();
  }
}

__global__ __launch_bounds__(512, 1) void lstm_kernel(
    const float* __restrict__ GxE, const float* __restrict__ GxD,
    const float* __restrict__ encWhh, const float* __restrict__ decWhh,
    float* __restrict__ hsteps, unsigned* __restrict__ regs)
{
  __shared__ float hl[2][576];
  __shared__ unsigned ltag[2];
  __shared__ float hcur[E];
  __shared__ int s_rank, s_mode;
  const int tid = threadIdx.x;

  if (tid==0){
    unsigned xcc;
    asm volatile("s_getreg_b32 %0, hwreg(HW_REG_XCC_ID)" : "=s"(xcc));
    xcc &= 0xffu;
    unsigned old = atomicCAS(&regs[0], 0u, xcc+1u);       // agent scope
    unsigned ch  = old ? old : (xcc+1u);
    int rank = -1;
    if (ch == xcc+1u) rank = (int)atomicAdd(&regs[1], 1u);
    int mode = 0;
    if (rank >= 0 && rank < NB){
      bool full = false;
      for (int it=0; it<(1<<14); ++it){
        if (__hip_atomic_load(&regs[1], __ATOMIC_RELAXED, __HIP_MEMORY_SCOPE_AGENT) >= (unsigned)NB){ full=true; break; }
        __builtin_amdgcn_s_sleep(16);
      }
      if (!full){ __hip_atomic_store(&regs[2], 1u, __ATOMIC_RELAXED, __HIP_MEMORY_SCOPE_AGENT); mode = 1; }
      else if (__hip_atomic_load(&regs[2], __ATOMIC_RELAXED, __HIP_MEMORY_SCOPE_AGENT)) mode = 1;
    } else rank = -1;
    s_rank = rank; s_mode = mode;
    ltag[0] = 0xFFFFFFFFu; ltag[1] = 0xFFFFFFFFu;
  }
  __syncthreads();
  const int rank = s_rank, mode = s_mode;
  if (rank < 0) return;
  if (mode){
    if (rank == 0) fallback_lstm(GxE, GxD, encWhh, decWhh, hsteps, hcur);
    return;
  }

  const int lane = tid & 63, wave = tid >> 6;
  const int g = lane >> 4, k = lane & 15;
  const int j = rank*8 + wave;                 // h element owned by this wave
  const int row = g*E + j;

  float w[32];
  loadw(encWhh, row, k, w);
  float cst = 0.f;
  for (int s=0; s<SLEN-1; ++s)
    fast_step(s, s, GxE, hsteps, hl, ltag, w, lane, wave, g, k, j, row, cst);

  // poison decode-era buffers (alias GxE head) before our step-127 store;
  // consumers gate on hsteps[128] completeness, so all poisons precede any read.
  if (lane==0){
    const float sf = __uint_as_float(SENT_U32);
    for (int u=SLEN+1; u<=NSTEPS; ++u){
      float* p = hsteps + (size_t)u*E + j;
      asm volatile("global_store_dword %0, %1, off sc0" :: "v"(p), "v"(sf) : "memory");
    }
  }
  asm volatile("s_waitcnt vmcnt(0)" ::: "memory");

  fast_step(SLEN-1, SLEN-1, GxE, hsteps, hl, ltag, w, lane, wave, g, k, j, row, cst);

  loadw(decWhh, row, k, w);
  cst = 0.f;
  for (int s=SLEN; s<NSTEPS; ++s)
    fast_step(s, s-SLEN, GxD, hsteps, hl, ltag, w, lane, wave, g, k, j, row, cst);
}

// =================== C1: logits GEMM + per-(t,chunk) softmax partials ===================
__global__ __launch_bounds__(128) void c1_kernel(
    const float* __restrict__ h_all, const float* __restrict__ W, const float* __restrict__ bvec,
    const int* __restrict__ tgt, float* __restrict__ pm, float* __restrict__ ps, float* __restrict__ tl)
{
  __shared__ float hst[32][E];
  const int tid  = threadIdx.x;
  const int wv   = tid >> 6, lane = tid & 63;
  const int chunk = blockIdx.x;
  const int t0    = blockIdx.y * 32;
  const int nt    = (t0 + 32 <= TLEN) ? 32 : (TLEN - t0);

  for (int idx = tid; idx < nt*(E/4); idx += 128)
    ((float4*)&hst[0][0])[idx] = ((const float4*)(h_all + (size_t)t0*E))[idx];
  __syncthreads();

  const int c0 = chunk*256 + tid;
  const int c1 = c0 + 128;
  const bool v0 = c0 < VT, v1 = c1 < VT;
  const float* w0 = W + (size_t)(v0 ? c0 : 0)*E;
  const float* w1 = W + (size_t)(v1 ? c1 : 0)*E;

  float acc0[32], acc1[32];
  #pragma unroll
  for (int i=0;i<32;++i){ acc0[i]=0.f; acc1[i]=0.f; }

  for (int kc=0; kc<E; kc+=4){
    float4 wa = *(const float4*)(w0+kc);
    float4 wb = *(const float4*)(w1+kc);
    #pragma unroll
    for (int tt=0; tt<32; ++tt){
      float4 h4 = *(const float4*)&hst[tt][kc];
      acc0[tt] += wa.x*h4.x + wa.y*h4.y + wa.z*h4.z + wa.w*h4.w;
      acc1[tt] += wb.x*h4.x + wb.y*h4.y + wb.z*h4.z + wb.w*h4.w;
    }
  }
  const float b0 = v0 ? bvec[c0] : 0.f;
  const float b1 = v1 ? bvec[c1] : 0.f;

  __syncthreads();
  float* red = &hst[0][0];

  #pragma unroll
  for (int tt=0; tt<32; ++tt){
    const bool act = tt < nt;
    float x0 = v0 ? acc0[tt]+b0 : -FLT_MAX;
    float x1 = v1 ? acc1[tt]+b1 : -FLT_MAX;
    float mx = fmaxf(x0,x1);
    #pragma unroll
    for (int off=1; off<64; off<<=1) mx = fmaxf(mx, __shfl_xor(mx, off));
    if (lane==0) red[wv] = mx;
    __syncthreads();
    mx = fmaxf(red[0], red[1]);
    float e = (v0 ? __expf(x0-mx) : 0.f) + (v1 ? __expf(x1-mx) : 0.f);
    #pragma unroll
    for (int off=1; off<64; off<<=1) e += __shfl_xor(e, off);
    if (lane==0) red[2+wv] = e;
    __syncthreads();
    float ssum = red[2] + red[3];
    if (act){
      int t = t0 + tt;
      if (tid==0){ pm[(size_t)chunk*TPAD + t] = mx; ps[(size_t)chunk*TPAD + t] = ssum; }
      int tok = (t < SLEN) ? tgt[t] : 1;
      if (v0 && c0==tok) tl[t] = x0;
      if (v1 && c1==tok) tl[t] = x1;
    }
    __syncthreads();
  }
}

// =================== C2: combine partials -> per-t loss -> sum ===================
__global__ __launch_bounds__(256) void c2_kernel(
    const float* __restrict__ pm, const float* __restrict__ ps, const float* __restrict__ tl,
    float* __restrict__ out)
{
  const int tid = threadIdx.x;
  float loss = 0.f;
  if (tid < TLEN){
    float m = -FLT_MAX, ssum = 0.f;
    for (int ch=0; ch<NCHUNK; ++ch){
      float mc = pm[(size_t)ch*TPAD + tid];
      float sc = ps[(size_t)ch*TPAD + tid];
      float nm = fmaxf(m, mc);
      ssum = ssum*__expf(m-nm) + sc*__expf(mc-nm);
      m = nm;
    }
    loss = (m + __logf(ssum)) - tl[tid];
  }
  __shared__ float red[4];
  #pragma unroll
  for (int off=1; off<64; off<<=1) loss += __shfl_xor(loss, off);
  if ((tid & 63)==0) red[tid>>6] = loss;
  __syncthreads();
  if (tid==0) out[0] = red[0]+red[1]+red[2]+red[3];
}

// =================== launch ===================
extern "C" void kernel_launch(void* const* d_in, const int* in_sizes, int n_in,
                              void* d_out, int out_size, void* d_ws, size_t ws_size,
                              hipStream_t stream)
{
  const int*   src    = (const int*)  d_in[0];
  const int*   tgt    = (const int*)  d_in[1];
  const float* Wx     = (const float*)d_in[2];
  const float* Wy     = (const float*)d_in[3];
  const float* encWih = (const float*)d_in[4];
  const float* encWhh = (const float*)d_in[5];
  const float* encBih = (const float*)d_in[6];
  const float* encBhh = (const float*)d_in[7];
  const float* decWih = (const float*)d_in[8];
  const float* decWhh = (const float*)d_in[9];
  const float* decBih = (const float*)d_in[10];
  const float* decBhh = (const float*)d_in[11];
  const float* Whr    = (const float*)d_in[12];
  const float* bhr    = (const float*)d_in[13];

  char* ws = (char*)d_ws;
  float* hsteps   = (float*)(ws + HS_OFF);
  float* GxE      = (float*)(ws + GXE_OFF);
  float* GxD      = (float*)(ws + GXD_OFF);
  float* hall     = (float*)(ws + HALL_OFF);
  float* pm       = (float*)(ws + PM_OFF);
  float* ps       = (float*)(ws + PS_OFF);
  float* tl       = (float*)(ws + TL_OFF);
  unsigned* regs  = (unsigned*)(ws + REG_OFF);

  hipMemsetAsync(ws + HS_OFF, 0x40, POISON_B, stream);  // sentinel-poison enc-era h buffers
  hipMemsetAsync(ws + REG_OFF, 0, 128, stream);         // registration state

  dim3 ggrid(33, 8);
  gx_kernel<<<ggrid, 256, 0, stream>>>(src, tgt, Wx, Wy,
      encWih, encBih, encBhh, decWih, decBih, decBhh, GxE, GxD);

  lstm_kernel<<<NGRID, 512, 0, stream>>>(GxE, GxD, encWhh, decWhh, hsteps, regs);

  dim3 cgrid(NCHUNK, 5);
  c1_kernel<<<cgrid, 128, 0, stream>>>(hall, Whr, bhr, tgt, pm, ps, tl);

  c2_kernel<<<1, 256, 0, stream>>>(pm, ps, tl, (float*)d_out);
}

// Round 8
// 1412.112 us; speedup vs baseline: 2120.2050x; 2120.2050x over previous
//
#include <hip/hip_runtime.h>
#include <cfloat>
#include <cmath>

#define E      512
#define FOURE  2048
#define VT     50000
#define SLEN   128
#define TLEN   129            // decoder steps (targets + EOS)
#define NSTEPS 257
#define NB     64             // persistent LSTM blocks (64 <= 256 CUs -> co-resident)
#define NINBOX 32             // replicated inboxes; block bid polls inbox bid>>1
#define NCHUNK 196
#define TPAD   132

// ---- workspace layout (bytes); total 2,367,488 <= 2,597,572 proven (r1) ----
#define INBOX_OFF  0            // u64 inboxes[32][2][512] = 262144; memset 0 each call
#define GXE_OFF    262144       // 128*2048 f32 = 1048576 -> ends 1310720
#define PM_OFF     262144       //   alias GxE head (c1 runs after lstm): 103488
#define PS_OFF     365632       //   103488
#define TL_OFF     469120       //   129 f32 -> ends 469636
#define HALL_OFF   786432       //   alias GxE rows 64..96 (dead in decode): 264192 -> ends 1050624
#define GXD_OFF    1310720      // 129*2048 f32 = 1056768 -> ends 2367488

__device__ __forceinline__ float sigf(float x){ return 1.0f/(1.0f+__expf(-x)); }
__device__ __forceinline__ float tanhf_fast(float x){ return 2.f*sigf(2.f*x) - 1.f; }

// =================== A: Gx[t][r] = x_t @ W_ih^T + b_ih + b_hh ===================
__global__ __launch_bounds__(256) void gx_kernel(
    const int* __restrict__ src, const int* __restrict__ tgt,
    const float* __restrict__ Wx, const float* __restrict__ Wy,
    const float* __restrict__ encWih, const float* __restrict__ encBih, const float* __restrict__ encBhh,
    const float* __restrict__ decWih, const float* __restrict__ decBih, const float* __restrict__ decBhh,
    float* __restrict__ GxE, float* __restrict__ GxD)
{
  __shared__ float xs[8][E];
  const int tid  = threadIdx.x;
  const int tile = blockIdx.x;
  const bool is_dec = tile >= 16;
  const int t0 = is_dec ? (tile-16)*8 : tile*8;
  const int T  = is_dec ? TLEN : SLEN;

  for (int tt=0; tt<8; ++tt){
    int t = t0+tt;
    if (t < T){
      const float* xrow;
      if (is_dec) xrow = (t==0) ? (Wx + (size_t)1*E) : (Wy + (size_t)tgt[t-1]*E);
      else        xrow = Wx + (size_t)src[t]*E;
      xs[tt][tid]     = xrow[tid];
      xs[tt][tid+256] = xrow[tid+256];
    }
  }
  __syncthreads();

  const int r = blockIdx.y*256 + tid;
  const float* wrow = (is_dec ? decWih : encWih) + (size_t)r*E;
  const float  bias = is_dec ? (decBih[r]+decBhh[r]) : (encBih[r]+encBhh[r]);
  float acc[8];
  #pragma unroll
  for (int i=0;i<8;++i) acc[i]=0.f;

  for (int kc=0; kc<E; kc+=4){
    float4 w = *(const float4*)(wrow+kc);
    #pragma unroll
    for (int tt=0; tt<8; ++tt){
      float4 x = *(const float4*)&xs[tt][kc];
      acc[tt] += w.x*x.x + w.y*x.y + w.z*x.z + w.w*x.w;
    }
  }
  float* Gx = is_dec ? GxD : GxE;
  #pragma unroll
  for (int tt=0; tt<8; ++tt){
    int t = t0+tt;
    if (t < T) Gx[(size_t)t*FOURE + r] = bias + acc[tt];
  }
}

// =================== B: tagged ping-pong inbox dataflow LSTM ===================
// 64 blocks x 8 waves; wave <-> h element j = bid*8+wave. lane: g=lane>>4
// (gate, torch order i,f,g,o), k=lane&15 (32-wide k slice).
// inbox slot = {tag:u32 hi, h bits:u32 lo}. End of step s publishes {s+1,h}
// into buffer (s+1)&1 of all 32 inboxes (lanes 0..31, 32 distinct lines).
// Back-pressure: reaching step s required seeing all tags==s, which proves
// everyone consumed tag s-1 -> overwriting buffer (s+1)&1 (holding tag s-1)
// is safe. Exact-match monotone tags; bounded spins; memset per call.
// Only wave0 polls globally; mirrors h into LDS hmir[s&1] (pidx padding:
// c -> c + 4*(c>>5), 2-way bank conflicts = free), releases ltag[s&1]=s.
__device__ __forceinline__ void load_weights(
    const float* __restrict__ Whh, float* __restrict__ wldsw, int j, int lane)
{
  #pragma unroll
  for (int gg=0; gg<4; ++gg){
    const float* wr = Whh + (size_t)(gg*E + j)*E;
    float4 a = *(const float4*)(wr + 4*lane);
    float4 b = *(const float4*)(wr + 4*lane + 256);
    float* dst = wldsw + (size_t)gg*E + (lane&7)*64 + (lane>>3)*4;
    *(float4*)dst      = a;   // wlds[g][q*64+4p+r] = W_row[32p+4q+r]
    *(float4*)(dst+32) = b;
  }
}

__global__ __launch_bounds__(512, 1) void lstm_kernel(
    const float* __restrict__ GxE, const float* __restrict__ GxD,
    const float* __restrict__ encWhh, const float* __restrict__ decWhh,
    unsigned long long* __restrict__ inboxes, float* __restrict__ h_all)
{
  __shared__ float wlds[8][4][E];           // 64 KiB, wave-private slices
  __shared__ float hmir[2][576];            // padded h mirror
  __shared__ unsigned ltag[2];
  const int tid  = threadIdx.x;
  const int lane = tid & 63, wave = tid >> 6, bid = blockIdx.x;
  const int g = lane >> 4, k = lane & 15;
  const int j = bid*8 + wave;
  const int row = g*E + j;
  float* wldsw = &wlds[wave][0][0];
  unsigned long long* myinbox = inboxes + (size_t)(bid>>1)*1024;

  if (tid == 0){ ltag[0] = 0u; ltag[1] = 0u; }
  load_weights(encWhh, wldsw, j, lane);
  __syncthreads();

  float cst = 0.f;
  for (int s=0; s<NSTEPS; ++s){
    if (s == SLEN){                         // enc -> dec boundary
      load_weights(decWhh, wldsw, j, lane); // wave-private region
      cst = 0.f;                            // reference resets cell state
    }
    const bool isdec = s >= SLEN;
    const int tloc = isdec ? (s - SLEN) : s;
    float gx = (isdec ? GxD : GxE)[(size_t)tloc*FOURE + row];

    float acc = 0.f;
    if (s > 0){
      const int buf = s & 1;
      if (wave == 0){
        const unsigned long long* hp = myinbox + (size_t)buf*512 + 8*lane;
        unsigned long long hu[8];
        for (int spin=0; spin<(1<<14); ++spin){
          #pragma unroll
          for (int q=0;q<8;++q)
            hu[q] = __hip_atomic_load(hp+q, __ATOMIC_RELAXED, __HIP_MEMORY_SCOPE_AGENT);
          bool ok = true;
          #pragma unroll
          for (int q=0;q<8;++q)
            ok = ok && ((unsigned)(hu[q]>>32) == (unsigned)s);
          if (__all(ok)) break;
          __builtin_amdgcn_s_sleep(1);
        }
        // mirror into LDS: slots 8*lane..8*lane+7 -> pidx = 8*lane + 4*(lane>>2)
        float* d = &hmir[buf][8*lane + 4*(lane>>2)];
        float4 lo, hi;
        lo.x = __uint_as_float((unsigned)hu[0]); lo.y = __uint_as_float((unsigned)hu[1]);
        lo.z = __uint_as_float((unsigned)hu[2]); lo.w = __uint_as_float((unsigned)hu[3]);
        hi.x = __uint_as_float((unsigned)hu[4]); hi.y = __uint_as_float((unsigned)hu[5]);
        hi.z = __uint_as_float((unsigned)hu[6]); hi.w = __uint_as_float((unsigned)hu[7]);
        *(float4*)d       = lo;
        *(float4*)(d + 4) = hi;
        if (lane == 0)
          __hip_atomic_store(&ltag[buf], (unsigned)s, __ATOMIC_RELEASE, __HIP_MEMORY_SCOPE_WORKGROUP);
      }
      for (int spin=0; spin<(1<<18); ++spin){
        if (__hip_atomic_load(&ltag[buf], __ATOMIC_ACQUIRE, __HIP_MEMORY_SCOPE_WORKGROUP) == (unsigned)s) break;
      }
      // dot: lane (g,k) needs h[32k+4i+r] = hmir[buf][36k+4i+r]
      const float* hb = &hmir[buf][36*k];
      #pragma unroll
      for (int i=0;i<8;++i){
        float4 h4 = *(const float4*)(hb + 4*i);
        float4 wv = *(const float4*)&wldsw[(size_t)g*E + i*64 + 4*k];
        acc += wv.x*h4.x + wv.y*h4.y + wv.z*h4.z + wv.w*h4.w;
      }
      // reduce over the 16 k-slice lanes (bits 0..3)
      acc += __shfl_xor(acc,1); acc += __shfl_xor(acc,2);
      acc += __shfl_xor(acc,4); acc += __shfl_xor(acc,8);
    }

    float gv = acc + gx;
    // all-gather the 4 gate values (bits 4..5)
    float x1 = __shfl_xor(gv,16);
    float x2 = __shfl_xor(gv,32);
    float x3 = __shfl_xor(x1,32);
    float gi = (g==0)?gv:(g==1)?x1:(g==2)?x2:x3;
    float gf = (g==0)?x1:(g==1)?gv:(g==2)?x3:x2;
    float gg = (g==0)?x2:(g==1)?x3:(g==2)?gv:x1;
    float go = (g==0)?x3:(g==1)?x2:(g==2)?x1:gv;
    cst = sigf(gf)*cst + sigf(gi)*tanhf_fast(gg);
    float hnew = sigf(go)*tanhf_fast(cst);

    // publish {s+1, h} to buffer (s+1)&1 of all 32 inboxes (lanes 0..31)
    unsigned long long pk = ((unsigned long long)(unsigned)(s+1) << 32)
                          |  (unsigned long long)__float_as_uint(hnew);
    if (lane < NINBOX)
      __hip_atomic_store(inboxes + (size_t)lane*1024 + (size_t)((s+1)&1)*512 + j,
                         pk, __ATOMIC_RELAXED, __HIP_MEMORY_SCOPE_AGENT);
    if (isdec && lane==0) h_all[(size_t)tloc*E + j] = hnew;
  }
}

// =================== C1: logits GEMM + per-(t,chunk) softmax partials ===================
__global__ __launch_bounds__(128) void c1_kernel(
    const float* __restrict__ h_all, const float* __restrict__ W, const float* __restrict__ bvec,
    const int* __restrict__ tgt, float* __restrict__ pm, float* __restrict__ ps, float* __restrict__ tl)
{
  __shared__ float hst[32][E];
  const int tid  = threadIdx.x;
  const int wv   = tid >> 6, lane = tid & 63;
  const int chunk = blockIdx.x;
  const int t0    = blockIdx.y * 32;
  const int nt    = (t0 + 32 <= TLEN) ? 32 : (TLEN - t0);

  for (int idx = tid; idx < nt*(E/4); idx += 128)
    ((float4*)&hst[0][0])[idx] = ((const float4*)(h_all + (size_t)t0*E))[idx];
  __syncthreads();

  const int c0 = chunk*256 + tid;
  const int c1 = c0 + 128;
  const bool v0 = c0 < VT, v1 = c1 < VT;
  const float* w0 = W + (size_t)(v0 ? c0 : 0)*E;
  const float* w1 = W + (size_t)(v1 ? c1 : 0)*E;

  float acc0[32], acc1[32];
  #pragma unroll
  for (int i=0;i<32;++i){ acc0[i]=0.f; acc1[i]=0.f; }

  for (int kc=0; kc<E; kc+=4){
    float4 wa = *(const float4*)(w0+kc);
    float4 wb = *(const float4*)(w1+kc);
    #pragma unroll
    for (int tt=0; tt<32; ++tt){
      float4 h4 = *(const float4*)&hst[tt][kc];
      acc0[tt] += wa.x*h4.x + wa.y*h4.y + wa.z*h4.z + wa.w*h4.w;
      acc1[tt] += wb.x*h4.x + wb.y*h4.y + wb.z*h4.z + wb.w*h4.w;
    }
  }
  const float b0 = v0 ? bvec[c0] : 0.f;
  const float b1 = v1 ? bvec[c1] : 0.f;

  __syncthreads();
  float* red = &hst[0][0];

  #pragma unroll
  for (int tt=0; tt<32; ++tt){
    const bool act = tt < nt;
    float x0 = v0 ? acc0[tt]+b0 : -FLT_MAX;
    float x1 = v1 ? acc1[tt]+b1 : -FLT_MAX;
    float mx = fmaxf(x0,x1);
    #pragma unroll
    for (int off=1; off<64; off<<=1) mx = fmaxf(mx, __shfl_xor(mx, off));
    if (lane==0) red[wv] = mx;
    __syncthreads();
    mx = fmaxf(red[0], red[1]);
    float e = (v0 ? __expf(x0-mx) : 0.f) + (v1 ? __expf(x1-mx) : 0.f);
    #pragma unroll
    for (int off=1; off<64; off<<=1) e += __shfl_xor(e, off);
    if (lane==0) red[2+wv] = e;
    __syncthreads();
    float ssum = red[2] + red[3];
    if (act){
      int t = t0 + tt;
      if (tid==0){ pm[(size_t)chunk*TPAD + t] = mx; ps[(size_t)chunk*TPAD + t] = ssum; }
      int tok = (t < SLEN) ? tgt[t] : 1;
      if (v0 && c0==tok) tl[t] = x0;
      if (v1 && c1==tok) tl[t] = x1;
    }
    __syncthreads();
  }
}

// =================== C2: combine partials -> per-t loss -> sum ===================
__global__ __launch_bounds__(256) void c2_kernel(
    const float* __restrict__ pm, const float* __restrict__ ps, const float* __restrict__ tl,
    float* __restrict__ out)
{
  const int tid = threadIdx.x;
  float loss = 0.f;
  if (tid < TLEN){
    float m = -FLT_MAX, ssum = 0.f;
    for (int ch=0; ch<NCHUNK; ++ch){
      float mc = pm[(size_t)ch*TPAD + tid];
      float sc = ps[(size_t)ch*TPAD + tid];
      float nm = fmaxf(m, mc);
      ssum = ssum*__expf(m-nm) + sc*__expf(mc-nm);
      m = nm;
    }
    loss = (m + __logf(ssum)) - tl[tid];
  }
  __shared__ float red[4];
  #pragma unroll
  for (int off=1; off<64; off<<=1) loss += __shfl_xor(loss, off);
  if ((tid & 63)==0) red[tid>>6] = loss;
  __syncthreads();
  if (tid==0) out[0] = red[0]+red[1]+red[2]+red[3];
}

// =================== launch ===================
extern "C" void kernel_launch(void* const* d_in, const int* in_sizes, int n_in,
                              void* d_out, int out_size, void* d_ws, size_t ws_size,
                              hipStream_t stream)
{
  const int*   src    = (const int*)  d_in[0];
  const int*   tgt    = (const int*)  d_in[1];
  const float* Wx     = (const float*)d_in[2];
  const float* Wy     = (const float*)d_in[3];
  const float* encWih = (const float*)d_in[4];
  const float* encWhh = (const float*)d_in[5];
  const float* encBih = (const float*)d_in[6];
  const float* encBhh = (const float*)d_in[7];
  const float* decWih = (const float*)d_in[8];
  const float* decWhh = (const float*)d_in[9];
  const float* decBih = (const float*)d_in[10];
  const float* decBhh = (const float*)d_in[11];
  const float* Whr    = (const float*)d_in[12];
  const float* bhr    = (const float*)d_in[13];

  char* ws = (char*)d_ws;
  unsigned long long* inboxes = (unsigned long long*)(ws + INBOX_OFF);
  float* GxE    = (float*)(ws + GXE_OFF);
  float* GxD    = (float*)(ws + GXD_OFF);
  float* hall   = (float*)(ws + HALL_OFF);   // aliases GxE rows 64..96 (dead in decode)
  float* pm     = (float*)(ws + PM_OFF);     // aliases GxE head (c1 runs after lstm)
  float* ps     = (float*)(ws + PS_OFF);
  float* tl     = (float*)(ws + TL_OFF);

  // reset inbox tags (graph-replay safe: stale tags from prior call would race)
  hipMemsetAsync(ws + INBOX_OFF, 0, NINBOX*1024*8, stream);

  dim3 ggrid(33, 8);
  gx_kernel<<<ggrid, 256, 0, stream>>>(src, tgt, Wx, Wy,
      encWih, encBih, encBhh, decWih, decBih, decBhh, GxE, GxD);

  lstm_kernel<<<NB, 512, 0, stream>>>(GxE, GxD, encWhh, decWhh, inboxes, hall);

  dim3 cgrid(NCHUNK, 5);
  c1_kernel<<<cgrid, 128, 0, stream>>>(hall, Whr, bhr, tgt, pm, ps, tl);

  c2_kernel<<<1, 256, 0, stream>>>(pm, ps, tl, (float*)d_out);
}